// Round 3
// baseline (358.115 us; speedup 1.0000x reference)
//
#include <hip/hip_runtime.h>

typedef _Float16 f16;
typedef __attribute__((ext_vector_type(4))) _Float16 f16x4;
typedef __attribute__((ext_vector_type(8))) _Float16 f16x8;
typedef __attribute__((ext_vector_type(4))) float f32x4;

#define GLB_AS __attribute__((address_space(1)))
#define LDS_AS __attribute__((address_space(3)))

__device__ __forceinline__ void async_copy16(const void* g, void* l) {
  // 16B-per-lane global->LDS DMA; LDS dest = wave-uniform base + lane*16
  __builtin_amdgcn_global_load_lds((const GLB_AS void*)g, (LDS_AS void*)l, 16, 0, 0);
}

// ---------------------------------------------------------------------------
// Generic fp16 GEMM: C[m][n] = sum_k A[m*lda+k] * B[n*ldb+k]   (both K-contig)
// BM=BN=128, BK=32, 256 threads (4 waves, 2x2), each wave 64x64 via 4x4 MFMA.
// 1D grid with explicit tile decode for XCD-aware L2 locality (XCD = n%8):
//  MODE 0 (projection): y-inner, (x,z)-outer -> XCD j owns row-slab y==j mod 8
//  MODE 1 (attention, ty=16, tz=4): z = (n%8)>>1 -> batch bound to an XCD pair
// Epilogue: 4-pass LDS round-trip (32 rows x 132-dword padded buffer) so the
// global C store is coalesced 16B-per-lane instead of 64 scattered stores.
// ---------------------------------------------------------------------------
template <typename OutT, int MODE, bool BIAS>
__global__ __launch_bounds__(256) void gemm_kn(
    const f16* __restrict__ A, const f16* __restrict__ B, OutT* __restrict__ C,
    int lda, int ldb, int ldc, int K, long sA, long sB, long sC,
    int tiles_x, int tiles_y,
    const float* __restrict__ b0, const float* __restrict__ b1,
    const float* __restrict__ b2)
{
  constexpr int BM = 128, BK = 32;
  // 16896 B: [0,8192) A-tile f16, [8192,16384) B-tile f16; epilogue reuses all
  // of it as a 32 x 132 fp32 buffer (132 stride -> 2 lanes/bank on writes).
  __shared__ __align__(16) float smemF[32 * 132];
  f16* Ash = (f16*)smemF;
  f16* Bsh = (f16*)smemF + BM * BK;

  int bx, by, bz;
  {
    const int n = blockIdx.x;
    if (MODE == 0) {
      by = n % tiles_y;
      const int r = n / tiles_y;
      bx = r % tiles_x;
      bz = r / tiles_x;
    } else {
      const int j = n & 7, i = n >> 3;
      bz = j >> 1;                     // batch <- XCD pair
      bx = i >> 3;                     // x-outer: B-tile resident per step
      by = (j & 1) * 8 + (i & 7);      // y-inner within this XCD's half
    }
  }

  A += (long)bz * sA;
  B += (long)bz * sB;
  C += (long)bz * sC;

  const int tid  = threadIdx.x;
  const int wave = tid >> 6, lane = tid & 63;
  const int m0 = by * BM, n0 = bx * BM;
  const int wm = (wave >> 1) * 64, wn = (wave & 1) * 64;
  const int r16 = lane & 15, quad = lane >> 4;

  // bias per output column (fp32, added pre-round; MODE0 only), hoisted
  float bias_j[4] = {0.f, 0.f, 0.f, 0.f};
  if (BIAS) {
    const float* bias = (bz == 0) ? b0 : (bz == 1) ? b1 : b2;
#pragma unroll
    for (int j = 0; j < 4; j++) bias_j[j] = bias[n0 + wn + j * 16 + r16];
  }

  // staging: each wave fills rows [wave*32, wave*32+32) of both tiles,
  // 2 chunks of 16 rows; lane l -> row +(l>>2), k-chunk (l&3)*8 elements (16B)
  const int srow = wave * 32 + (lane >> 2);
  const int skb  = (lane & 3) * 8;
  const f16* Ag = A + (long)(m0 + srow) * lda + skb;
  const f16* Bg = B + (long)(n0 + srow) * ldb + skb;
  f16* As0 = &Ash[(wave * 32) * BK];
  f16* As1 = &Ash[(wave * 32 + 16) * BK];
  f16* Bs0 = &Bsh[(wave * 32) * BK];
  f16* Bs1 = &Bsh[(wave * 32 + 16) * BK];

  f32x4 acc[4][4] = {};

  for (int k0 = 0; k0 < K; k0 += BK) {
    async_copy16(Ag + k0,                  As0);
    async_copy16(Ag + k0 + 16 * (long)lda, As1);
    async_copy16(Bg + k0,                  Bs0);
    async_copy16(Bg + k0 + 16 * (long)ldb, Bs1);
    __syncthreads();  // drains vmcnt (global_load_lds) + barrier

    f16x8 af[4], bf[4];
#pragma unroll
    for (int i = 0; i < 4; i++) {
      af[i] = *(const f16x8*)&Ash[(wm + i * 16 + r16) * BK + quad * 8];
      bf[i] = *(const f16x8*)&Bsh[(wn + i * 16 + r16) * BK + quad * 8];
    }
#pragma unroll
    for (int i = 0; i < 4; i++)
#pragma unroll
      for (int j = 0; j < 4; j++)
        acc[i][j] = __builtin_amdgcn_mfma_f32_16x16x32_f16(af[i], bf[j], acc[i][j], 0, 0, 0);
    __syncthreads();
  }

  // ---- epilogue: 4 passes of 32 rows through padded fp32 LDS --------------
  // C/D layout (verified m89): col = lane&15, row = (lane>>4)*4 + reg
  float* Ep = smemF;                       // 32 rows x 132 stride
#pragma unroll
  for (int p = 0; p < 4; p++) {
    if ((wm >> 6) == (p >> 1)) {           // this wave owns these 32 rows
      const int i0 = (p & 1) * 2;
#pragma unroll
      for (int ii = 0; ii < 2; ii++)
#pragma unroll
        for (int j = 0; j < 4; j++)
#pragma unroll
          for (int r = 0; r < 4; r++) {
            const int rl = ii * 16 + quad * 4 + r;     // 0..31
            const int cl = wn + j * 16 + r16;          // 0..127
            Ep[rl * 132 + cl] = acc[i0 + ii][j][r] + bias_j[j];
          }
    }
    __syncthreads();
    {
      const int row = tid >> 3, c0 = (tid & 7) * 16;
      const long grow = (long)(m0 + p * 32 + row) * ldc + n0 + c0;
      const float* src = &Ep[row * 132 + c0];
      f32x4 v0 = *(const f32x4*)(src + 0);
      f32x4 v1 = *(const f32x4*)(src + 4);
      f32x4 v2 = *(const f32x4*)(src + 8);
      f32x4 v3 = *(const f32x4*)(src + 12);
      if constexpr (sizeof(OutT) == 2) {
        f16x8 h0, h1;
        h0[0]=(f16)v0[0]; h0[1]=(f16)v0[1]; h0[2]=(f16)v0[2]; h0[3]=(f16)v0[3];
        h0[4]=(f16)v1[0]; h0[5]=(f16)v1[1]; h0[6]=(f16)v1[2]; h0[7]=(f16)v1[3];
        h1[0]=(f16)v2[0]; h1[1]=(f16)v2[1]; h1[2]=(f16)v2[2]; h1[3]=(f16)v2[3];
        h1[4]=(f16)v3[0]; h1[5]=(f16)v3[1]; h1[6]=(f16)v3[2]; h1[7]=(f16)v3[3];
        *(f16x8*)((f16*)C + grow)     = h0;
        *(f16x8*)((f16*)C + grow + 8) = h1;
      } else {
        float* dst = (float*)C + grow;
        *(f32x4*)(dst + 0)  = v0;
        *(f32x4*)(dst + 4)  = v1;
        *(f32x4*)(dst + 8)  = v2;
        *(f32x4*)(dst + 12) = v3;
      }
    }
    __syncthreads();
  }
}

// ---------------------------------------------------------------------------
// One launch casts x (8.39M) + Wq/Wk/Wv (1.05M each) fp32 -> fp16.
__global__ __launch_bounds__(256) void cast_all(
    const float* __restrict__ x, const float* __restrict__ Wq,
    const float* __restrict__ Wk, const float* __restrict__ Wv,
    f16* __restrict__ Xh, f16* __restrict__ Wh)
{
  const long off = (long)blockIdx.x * 1024 + threadIdx.x * 4;
  const float* src;
  f16* dst;
  if (off < 8388608L) {
    src = x + off;
    dst = Xh + off;
  } else {
    const long o = off - 8388608L;
    src = (o < 1048576L) ? Wq + o
        : (o < 2097152L) ? Wk + (o - 1048576L)
                         : Wv + (o - 2097152L);
    dst = Wh + o;
  }
  const float4 v = *(const float4*)src;
  f16x4 h;
  h.x = (f16)v.x; h.y = (f16)v.y; h.z = (f16)v.z; h.w = (f16)v.w;
  *(f16x4*)dst = h;
}

// LayerNorm (gamma/beta; bias already folded into GEMM epilogue).
// One block per row, in-place fp16. grid (8192, 3)
__global__ __launch_bounds__(256) void ln_kernel(
    f16* __restrict__ P, const float* __restrict__ gamma,
    const float* __restrict__ beta)
{
  f16* p = P + (long)blockIdx.y * 8388608 + (long)blockIdx.x * 1024;
  const int tid = threadIdx.x;
  const int e = tid * 4;

  f16x4 raw = *(const f16x4*)(p + e);
  float v0 = (float)raw.x, v1 = (float)raw.y;
  float v2 = (float)raw.z, v3 = (float)raw.w;
  float s  = v0 + v1 + v2 + v3;
  float s2 = v0 * v0 + v1 * v1 + v2 * v2 + v3 * v3;

#pragma unroll
  for (int off = 32; off > 0; off >>= 1) {
    s  += __shfl_down(s, off, 64);
    s2 += __shfl_down(s2, off, 64);
  }
  __shared__ float red[10];
  const int wave = tid >> 6, lane = tid & 63;
  if (lane == 0) { red[wave] = s; red[4 + wave] = s2; }
  __syncthreads();
  if (tid == 0) {
    red[8] = red[0] + red[1] + red[2] + red[3];
    red[9] = red[4] + red[5] + red[6] + red[7];
  }
  __syncthreads();
  const float mu   = red[8] * (1.f / 1024.f);
  const float var  = red[9] * (1.f / 1024.f) - mu * mu;
  const float rstd = rsqrtf(var + 1e-5f);

  float4 gg = *(const float4*)(gamma + e);
  float4 be = *(const float4*)(beta + e);
  f16x4 o;
  o.x = (f16)((v0 - mu) * rstd * gg.x + be.x);
  o.y = (f16)((v1 - mu) * rstd * gg.y + be.y);
  o.z = (f16)((v2 - mu) * rstd * gg.z + be.z);
  o.w = (f16)((v3 - mu) * rstd * gg.w + be.w);
  *(f16x4*)(p + e) = o;
}

// V (S x D, fp16) -> Vt (D x S, fp16), per batch. grid (D/64, S/64, B)
__global__ __launch_bounds__(256) void transpose_kernel(const f16* __restrict__ V,
                                                        f16* __restrict__ Vt)
{
  const int S = 2048, D = 1024;
  const f16* v = V + (long)blockIdx.z * ((long)S * D);
  f16* vt = Vt + (long)blockIdx.z * ((long)D * S);
  __shared__ f16 tile[64][66];  // +2 pad -> conflict-free transposed reads
  const int d0 = blockIdx.x * 64, j0 = blockIdx.y * 64;
  const int tx = threadIdx.x & 63, ty = threadIdx.x >> 6;
#pragma unroll
  for (int r = ty; r < 64; r += 4)
    tile[r][tx] = v[(long)(j0 + r) * D + d0 + tx];
  __syncthreads();
#pragma unroll
  for (int r = ty; r < 64; r += 4)
    vt[(long)(d0 + r) * S + j0 + tx] = tile[tx][r];
}

// Row softmax over 2048 fp32 logits; writes fp16 probs in-place (first half of row).
__global__ __launch_bounds__(256) void softmax_kernel(float* __restrict__ Sc)
{
  float* srow = Sc + (long)blockIdx.x * 2048;
  const int tid = threadIdx.x;
  float4 a = ((const float4*)srow)[tid];
  float4 b = ((const float4*)srow)[256 + tid];

  float m = fmaxf(fmaxf(fmaxf(a.x, a.y), fmaxf(a.z, a.w)),
                  fmaxf(fmaxf(b.x, b.y), fmaxf(b.z, b.w)));
#pragma unroll
  for (int off = 32; off > 0; off >>= 1) m = fmaxf(m, __shfl_down(m, off, 64));
  __shared__ float red[6];
  const int wave = tid >> 6, lane = tid & 63;
  if (lane == 0) red[wave] = m;
  __syncthreads();
  if (tid == 0) red[4] = fmaxf(fmaxf(red[0], red[1]), fmaxf(red[2], red[3]));
  __syncthreads();
  const float M = red[4];

  a.x = __expf(a.x - M); a.y = __expf(a.y - M);
  a.z = __expf(a.z - M); a.w = __expf(a.w - M);
  b.x = __expf(b.x - M); b.y = __expf(b.y - M);
  b.z = __expf(b.z - M); b.w = __expf(b.w - M);
  float s = a.x + a.y + a.z + a.w + b.x + b.y + b.z + b.w;
#pragma unroll
  for (int off = 32; off > 0; off >>= 1) s += __shfl_down(s, off, 64);
  if (lane == 0) red[wave] = s;
  __syncthreads();
  if (tid == 0) red[5] = red[0] + red[1] + red[2] + red[3];
  __syncthreads();
  const float inv = 1.0f / red[5];

  f16* orow = (f16*)srow;  // safe: all reads happened before first barrier
  f16x4 oa, ob;
  oa.x = (f16)(a.x * inv); oa.y = (f16)(a.y * inv);
  oa.z = (f16)(a.z * inv); oa.w = (f16)(a.w * inv);
  ob.x = (f16)(b.x * inv); ob.y = (f16)(b.y * inv);
  ob.z = (f16)(b.z * inv); ob.w = (f16)(b.w * inv);
  ((f16x4*)orow)[tid]       = oa;
  ((f16x4*)orow)[256 + tid] = ob;
}

// ---------------------------------------------------------------------------
extern "C" void kernel_launch(void* const* d_in, const int* in_sizes, int n_in,
                              void* d_out, int out_size, void* d_ws, size_t ws_size,
                              hipStream_t stream)
{
  const float* x     = (const float*)d_in[0];
  const float* Wq    = (const float*)d_in[1];
  const float* bq    = (const float*)d_in[2];
  const float* Wk    = (const float*)d_in[3];
  const float* bk    = (const float*)d_in[4];
  const float* Wv    = (const float*)d_in[5];
  const float* bv    = (const float*)d_in[6];
  const float* gamma = (const float*)d_in[7];
  const float* beta  = (const float*)d_in[8];
  float* out = (float*)d_out;

  // ws layout (needs 128 MB):
  //  [0,48)MB   P  : Q,K,V fp16 slabs (8192x1024 each), LN in-place
  //  [48,64)MB  Vt : V transposed per batch (1024x2048 fp16)
  //  [64,128)MB Sc : scores fp32 (4 x 2048x2048); softmax writes fp16 probs in-place
  //  Xh/Wh aliased inside the Sc region (dead before scores are written)
  char* ws = (char*)d_ws;
  f16*   P  = (f16*)(ws);
  f16*   Vt = (f16*)(ws + (48u << 20));
  float* Sc = (float*)(ws + (64u << 20));
  f16*   Xh = (f16*)(ws + (64u << 20));
  f16*   Wh = (f16*)(ws + (80u << 20));

  // 1. fp32 -> fp16 casts (single launch)
  cast_all<<<11264, 256, 0, stream>>>(x, Wq, Wk, Wv, Xh, Wh);

  // 2. projections + bias: P_h = Xh · Wh^T + b_h  (M=8192, N=1024, K=1024, z=h)
  gemm_kn<f16, 0, true><<<1536, 256, 0, stream>>>(
      Xh, Wh, P, 1024, 1024, 1024, 1024, 0L, 1048576L, 8388608L,
      8, 64, bq, bk, bv);

  // 3. LayerNorm (gamma/beta), in-place fp16
  ln_kernel<<<dim3(8192, 3), 256, 0, stream>>>(P, gamma, beta);

  // 4. V -> Vt per batch
  transpose_kernel<<<dim3(16, 32, 4), 256, 0, stream>>>(P + 2L * 8388608, Vt);

  // 5. scores: Sc_b = Q_b · K_b^T  (M=N=2048, K=1024, z=batch, fp32 out)
  gemm_kn<float, 1, false><<<1024, 256, 0, stream>>>(
      P, P + 8388608, Sc, 1024, 1024, 2048, 1024, 2097152L, 2097152L, 4194304L,
      16, 16, nullptr, nullptr, nullptr);

  // 6. softmax rows (8192 rows), fp16 probs in-place (row pitch 4096 halves)
  softmax_kernel<<<8192, 256, 0, stream>>>(Sc);

  // 7. out_b = Pr_b · Vt_b^T  (M=2048, N=1024, K=2048, z=batch, fp32 out)
  gemm_kn<float, 1, false><<<512, 256, 0, stream>>>(
      (const f16*)Sc, Vt, out, 4096, 2048, 1024, 2048, 8388608L, 2097152L, 2097152L,
      8, 16, nullptr, nullptr, nullptr);
}

// Round 4
// 309.446 us; speedup vs baseline: 1.1573x; 1.1573x over previous
//
#include <hip/hip_runtime.h>

typedef _Float16 f16;
typedef __attribute__((ext_vector_type(4))) _Float16 f16x4;
typedef __attribute__((ext_vector_type(8))) _Float16 f16x8;
typedef __attribute__((ext_vector_type(4))) float f32x4;

#define GLB_AS __attribute__((address_space(1)))
#define LDS_AS __attribute__((address_space(3)))

__device__ __forceinline__ void async_copy16(const void* g, void* l) {
  // 16B-per-lane global->LDS DMA; LDS dest = wave-uniform base + lane*16
  __builtin_amdgcn_global_load_lds((const GLB_AS void*)g, (LDS_AS void*)l, 16, 0, 0);
}

// ---------------------------------------------------------------------------
// Generic fp16 GEMM: C[m][n] = sum_k A[m*lda+k] * B[n*ldb+k]   (both K-contig)
// BM=BN=128, BK=32, 256 threads (4 waves, 2x2), each wave 64x64 via 4x4 MFMA.
// Double-buffered LDS: prefetch tile k+1 right after the barrier, compute
// tile k -> ONE barrier per iteration and the vmcnt(0) drain overlaps the
// whole MFMA body instead of being exposed back-to-back with the loads.
// 1D grid with explicit tile decode for XCD-aware L2 locality (XCD = n%8):
//  MODE 0 (projection): y-inner, (x,z)-outer -> XCD j owns row-slab y==j mod 8
//  MODE 1 (attention, ty=16, tz=4): z = (n%8)>>1 -> batch bound to an XCD pair
// ---------------------------------------------------------------------------
template <typename OutT, int MODE, bool BIAS>
__global__ __launch_bounds__(256) void gemm_kn(
    const f16* __restrict__ A, const f16* __restrict__ B, OutT* __restrict__ C,
    int lda, int ldb, int ldc, int K, long sA, long sB, long sC,
    int tiles_x, int tiles_y,
    const float* __restrict__ b0, const float* __restrict__ b1,
    const float* __restrict__ b2)
{
  constexpr int BM = 128, BK = 32;
  __shared__ __align__(16) f16 Ash[2][BM * BK];
  __shared__ __align__(16) f16 Bsh[2][BM * BK];

  int bx, by, bz;
  {
    const int n = blockIdx.x;
    if (MODE == 0) {
      by = n % tiles_y;
      const int r = n / tiles_y;
      bx = r % tiles_x;
      bz = r / tiles_x;
    } else {
      const int j = n & 7, i = n >> 3;
      bz = j >> 1;                     // batch <- XCD pair
      bx = i >> 3;                     // x-outer: B-tile resident per step
      by = (j & 1) * 8 + (i & 7);      // y-inner within this XCD's half
    }
  }

  A += (long)bz * sA;
  B += (long)bz * sB;
  C += (long)bz * sC;

  const int tid  = threadIdx.x;
  const int wave = tid >> 6, lane = tid & 63;
  const int m0 = by * BM, n0 = bx * BM;
  const int wm = (wave >> 1) * 64, wn = (wave & 1) * 64;
  const int r16 = lane & 15, quad = lane >> 4;

  // staging: each wave fills rows [wave*32, wave*32+32) of both tiles,
  // 2 chunks of 16 rows; lane l -> row +(l>>2), k-chunk (l&3)*8 elements (16B)
  const int srow = wave * 32 + (lane >> 2);
  const int skb  = (lane & 3) * 8;
  const f16* Ag = A + (long)(m0 + srow) * lda + skb;
  const f16* Bg = B + (long)(n0 + srow) * ldb + skb;
  const int lo0 = (wave * 32) * BK;        // LDS row offset, 16-row chunk 0
  const int lo1 = (wave * 32 + 16) * BK;   // chunk 1

  // prologue: fill buffer 0
  async_copy16(Ag,                  &Ash[0][lo0]);
  async_copy16(Ag + 16 * (long)lda, &Ash[0][lo1]);
  async_copy16(Bg,                  &Bsh[0][lo0]);
  async_copy16(Bg + 16 * (long)ldb, &Bsh[0][lo1]);

  f32x4 acc[4][4] = {};

  int buf = 0;
  for (int k0 = 0; k0 < K; k0 += BK, buf ^= 1) {
    __syncthreads();  // vmcnt(0): prefetch landed; all waves done with buf^1

    if (k0 + BK < K) {
      const int nb = buf ^ 1;
      const long k1 = k0 + BK;
      async_copy16(Ag + k1,                  &Ash[nb][lo0]);
      async_copy16(Ag + k1 + 16 * (long)lda, &Ash[nb][lo1]);
      async_copy16(Bg + k1,                  &Bsh[nb][lo0]);
      async_copy16(Bg + k1 + 16 * (long)ldb, &Bsh[nb][lo1]);
    }

    f16x8 af[4], bf[4];
#pragma unroll
    for (int i = 0; i < 4; i++) {
      af[i] = *(const f16x8*)&Ash[buf][(wm + i * 16 + r16) * BK + quad * 8];
      bf[i] = *(const f16x8*)&Bsh[buf][(wn + i * 16 + r16) * BK + quad * 8];
    }
#pragma unroll
    for (int i = 0; i < 4; i++)
#pragma unroll
      for (int j = 0; j < 4; j++)
        acc[i][j] = __builtin_amdgcn_mfma_f32_16x16x32_f16(af[i], bf[j], acc[i][j], 0, 0, 0);
  }

  // C/D layout (verified m89): col = lane&15, row = (lane>>4)*4 + reg
  float bias_j[4] = {0.f, 0.f, 0.f, 0.f};
  if (BIAS) {
    const float* bias = (bz == 0) ? b0 : (bz == 1) ? b1 : b2;
#pragma unroll
    for (int j = 0; j < 4; j++) bias_j[j] = bias[n0 + wn + j * 16 + r16];
  }
#pragma unroll
  for (int i = 0; i < 4; i++)
#pragma unroll
    for (int j = 0; j < 4; j++)
#pragma unroll
      for (int r = 0; r < 4; r++) {
        long row = m0 + wm + i * 16 + quad * 4 + r;
        long col = n0 + wn + j * 16 + r16;
        C[row * (long)ldc + col] = (OutT)(acc[i][j][r] + bias_j[j]);
      }
}

// ---------------------------------------------------------------------------
// One launch casts x (8.39M) + Wq/Wk/Wv (1.05M each) fp32 -> fp16.
__global__ __launch_bounds__(256) void cast_all(
    const float* __restrict__ x, const float* __restrict__ Wq,
    const float* __restrict__ Wk, const float* __restrict__ Wv,
    f16* __restrict__ Xh, f16* __restrict__ Wh)
{
  const long off = (long)blockIdx.x * 1024 + threadIdx.x * 4;
  const float* src;
  f16* dst;
  if (off < 8388608L) {
    src = x + off;
    dst = Xh + off;
  } else {
    const long o = off - 8388608L;
    src = (o < 1048576L) ? Wq + o
        : (o < 2097152L) ? Wk + (o - 1048576L)
                         : Wv + (o - 2097152L);
    dst = Wh + o;
  }
  const float4 v = *(const float4*)src;
  f16x4 h;
  h.x = (f16)v.x; h.y = (f16)v.y; h.z = (f16)v.z; h.w = (f16)v.w;
  *(f16x4*)dst = h;
}

// LayerNorm (gamma/beta; bias already folded into GEMM epilogue).
// One block per row, in-place fp16. grid (8192, 3)
__global__ __launch_bounds__(256) void ln_kernel(
    f16* __restrict__ P, const float* __restrict__ gamma,
    const float* __restrict__ beta)
{
  f16* p = P + (long)blockIdx.y * 8388608 + (long)blockIdx.x * 1024;
  const int tid = threadIdx.x;
  const int e = tid * 4;

  f16x4 raw = *(const f16x4*)(p + e);
  float v0 = (float)raw.x, v1 = (float)raw.y;
  float v2 = (float)raw.z, v3 = (float)raw.w;
  float s  = v0 + v1 + v2 + v3;
  float s2 = v0 * v0 + v1 * v1 + v2 * v2 + v3 * v3;

#pragma unroll
  for (int off = 32; off > 0; off >>= 1) {
    s  += __shfl_down(s, off, 64);
    s2 += __shfl_down(s2, off, 64);
  }
  __shared__ float red[10];
  const int wave = tid >> 6, lane = tid & 63;
  if (lane == 0) { red[wave] = s; red[4 + wave] = s2; }
  __syncthreads();
  if (tid == 0) {
    red[8] = red[0] + red[1] + red[2] + red[3];
    red[9] = red[4] + red[5] + red[6] + red[7];
  }
  __syncthreads();
  const float mu   = red[8] * (1.f / 1024.f);
  const float var  = red[9] * (1.f / 1024.f) - mu * mu;
  const float rstd = rsqrtf(var + 1e-5f);

  float4 gg = *(const float4*)(gamma + e);
  float4 be = *(const float4*)(beta + e);
  f16x4 o;
  o.x = (f16)((v0 - mu) * rstd * gg.x + be.x);
  o.y = (f16)((v1 - mu) * rstd * gg.y + be.y);
  o.z = (f16)((v2 - mu) * rstd * gg.z + be.z);
  o.w = (f16)((v3 - mu) * rstd * gg.w + be.w);
  *(f16x4*)(p + e) = o;
}

// V (S x D, fp16) -> Vt (D x S, fp16), per batch. grid (D/64, S/64, B)
__global__ __launch_bounds__(256) void transpose_kernel(const f16* __restrict__ V,
                                                        f16* __restrict__ Vt)
{
  const int S = 2048, D = 1024;
  const f16* v = V + (long)blockIdx.z * ((long)S * D);
  f16* vt = Vt + (long)blockIdx.z * ((long)D * S);
  __shared__ f16 tile[64][66];  // +2 pad -> conflict-free transposed reads
  const int d0 = blockIdx.x * 64, j0 = blockIdx.y * 64;
  const int tx = threadIdx.x & 63, ty = threadIdx.x >> 6;
#pragma unroll
  for (int r = ty; r < 64; r += 4)
    tile[r][tx] = v[(long)(j0 + r) * D + d0 + tx];
  __syncthreads();
#pragma unroll
  for (int r = ty; r < 64; r += 4)
    vt[(long)(d0 + r) * S + j0 + tx] = tile[tx][r];
}

// Row softmax over 2048 fp32 logits; writes fp16 probs in-place (first half of row).
__global__ __launch_bounds__(256) void softmax_kernel(float* __restrict__ Sc)
{
  float* srow = Sc + (long)blockIdx.x * 2048;
  const int tid = threadIdx.x;
  float4 a = ((const float4*)srow)[tid];
  float4 b = ((const float4*)srow)[256 + tid];

  float m = fmaxf(fmaxf(fmaxf(a.x, a.y), fmaxf(a.z, a.w)),
                  fmaxf(fmaxf(b.x, b.y), fmaxf(b.z, b.w)));
#pragma unroll
  for (int off = 32; off > 0; off >>= 1) m = fmaxf(m, __shfl_down(m, off, 64));
  __shared__ float red[6];
  const int wave = tid >> 6, lane = tid & 63;
  if (lane == 0) red[wave] = m;
  __syncthreads();
  if (tid == 0) red[4] = fmaxf(fmaxf(red[0], red[1]), fmaxf(red[2], red[3]));
  __syncthreads();
  const float M = red[4];

  a.x = __expf(a.x - M); a.y = __expf(a.y - M);
  a.z = __expf(a.z - M); a.w = __expf(a.w - M);
  b.x = __expf(b.x - M); b.y = __expf(b.y - M);
  b.z = __expf(b.z - M); b.w = __expf(b.w - M);
  float s = a.x + a.y + a.z + a.w + b.x + b.y + b.z + b.w;
#pragma unroll
  for (int off = 32; off > 0; off >>= 1) s += __shfl_down(s, off, 64);
  if (lane == 0) red[wave] = s;
  __syncthreads();
  if (tid == 0) red[5] = red[0] + red[1] + red[2] + red[3];
  __syncthreads();
  const float inv = 1.0f / red[5];

  f16* orow = (f16*)srow;  // safe: all reads happened before first barrier
  f16x4 oa, ob;
  oa.x = (f16)(a.x * inv); oa.y = (f16)(a.y * inv);
  oa.z = (f16)(a.z * inv); oa.w = (f16)(a.w * inv);
  ob.x = (f16)(b.x * inv); ob.y = (f16)(b.y * inv);
  ob.z = (f16)(b.z * inv); ob.w = (f16)(b.w * inv);
  ((f16x4*)orow)[tid]       = oa;
  ((f16x4*)orow)[256 + tid] = ob;
}

// ---------------------------------------------------------------------------
extern "C" void kernel_launch(void* const* d_in, const int* in_sizes, int n_in,
                              void* d_out, int out_size, void* d_ws, size_t ws_size,
                              hipStream_t stream)
{
  const float* x     = (const float*)d_in[0];
  const float* Wq    = (const float*)d_in[1];
  const float* bq    = (const float*)d_in[2];
  const float* Wk    = (const float*)d_in[3];
  const float* bk    = (const float*)d_in[4];
  const float* Wv    = (const float*)d_in[5];
  const float* bv    = (const float*)d_in[6];
  const float* gamma = (const float*)d_in[7];
  const float* beta  = (const float*)d_in[8];
  float* out = (float*)d_out;

  // ws layout (needs 128 MB):
  //  [0,48)MB   P  : Q,K,V fp16 slabs (8192x1024 each), LN in-place
  //  [48,64)MB  Vt : V transposed per batch (1024x2048 fp16)
  //  [64,128)MB Sc : scores fp32 (4 x 2048x2048); softmax writes fp16 probs in-place
  //  Xh/Wh aliased inside the Sc region (dead before scores are written)
  char* ws = (char*)d_ws;
  f16*   P  = (f16*)(ws);
  f16*   Vt = (f16*)(ws + (48u << 20));
  float* Sc = (float*)(ws + (64u << 20));
  f16*   Xh = (f16*)(ws + (64u << 20));
  f16*   Wh = (f16*)(ws + (80u << 20));

  // 1. fp32 -> fp16 casts (single launch)
  cast_all<<<11264, 256, 0, stream>>>(x, Wq, Wk, Wv, Xh, Wh);

  // 2. projections + bias: P_h = Xh · Wh^T + b_h  (M=8192, N=1024, K=1024, z=h)
  gemm_kn<f16, 0, true><<<1536, 256, 0, stream>>>(
      Xh, Wh, P, 1024, 1024, 1024, 1024, 0L, 1048576L, 8388608L,
      8, 64, bq, bk, bv);

  // 3. LayerNorm (gamma/beta), in-place fp16
  ln_kernel<<<dim3(8192, 3), 256, 0, stream>>>(P, gamma, beta);

  // 4. V -> Vt per batch
  transpose_kernel<<<dim3(16, 32, 4), 256, 0, stream>>>(P + 2L * 8388608, Vt);

  // 5. scores: Sc_b = Q_b · K_b^T  (M=N=2048, K=1024, z=batch, fp32 out)
  gemm_kn<float, 1, false><<<1024, 256, 0, stream>>>(
      P, P + 8388608, Sc, 1024, 1024, 2048, 1024, 2097152L, 2097152L, 4194304L,
      16, 16, nullptr, nullptr, nullptr);

  // 6. softmax rows (8192 rows), fp16 probs in-place (row pitch 4096 halves)
  softmax_kernel<<<8192, 256, 0, stream>>>(Sc);

  // 7. out_b = Pr_b · Vt_b^T  (M=2048, N=1024, K=2048, z=batch, fp32 out)
  gemm_kn<float, 1, false><<<512, 256, 0, stream>>>(
      (const f16*)Sc, Vt, out, 4096, 2048, 1024, 2048, 8388608L, 2097152L, 2097152L,
      8, 16, nullptr, nullptr, nullptr);
}